// Round 4
// baseline (301.848 us; speedup 1.0000x reference)
//
#include <hip/hip_runtime.h>
#include <hip/hip_bf16.h>

typedef __hip_bfloat16 bf16;
typedef unsigned short u16;
typedef short bf16x8 __attribute__((ext_vector_type(8)));
typedef float f32x4  __attribute__((ext_vector_type(4)));

// problem constants (fixed instance)
#define BB    2
#define LL    6
#define NWIN  64     // X*Y
#define PP    49     // w1*w2
#define DIMM  256
#define HEADS 8
#define CHN   32
#define SS    294    // LL*PP
#define ASTRIDE 264  // LDS A-tile row stride in u16
#define BSTRIDE 304  // biasM row stride (f32)

__device__ __forceinline__ u16 bfbits(float x) { return __bfloat16_as_ushort(__float2bfloat16(x)); }
__device__ __forceinline__ f32x4 mfma16(bf16x8 a, bf16x8 b, f32x4 c) {
    return __builtin_amdgcn_mfma_f32_16x16x32_bf16(a, b, c, 0, 0, 0);
}

// ---------------- merged prep kernel ----------------
// blocks [0,1792): W transpose+convert; [1792,1920): rel weights; [1920,4713): bias matrix
__global__ __launch_bounds__(256) void k_prep(
    const float* __restrict__ Wq, const float* __restrict__ Wk, const float* __restrict__ Wv,
    const float* __restrict__ Wo, const float* __restrict__ ra, const float* __restrict__ rm,
    const float* __restrict__ bt,
    u16* __restrict__ wT, u16* __restrict__ Wob, u16* __restrict__ raT, u16* __restrict__ rmb,
    float* __restrict__ biasM)
{
    const int blk = blockIdx.x;
    if (blk < 1792) {
        const int idx = blk*256 + threadIdx.x;
        if (idx >= 7*65536) return;
        const int mat = idx >> 16, rem = idx & 65535;
        if (mat < 6) {
            const int tz = mat >> 1, t = mat & 1;
            const int e = rem >> 8, d = rem & 255;
            const float* W = (tz == 0 ? Wq : tz == 1 ? Wk : Wv);
            wT[mat*65536 + rem] = bfbits(W[t*65536 + d*256 + e]);
        } else {
            Wob[rem] = bfbits(Wo[rem]);
        }
    } else if (blk < 1920) {
        const int idx = (blk - 1792)*256 + threadIdx.x;
        if (idx < 4*HEADS*CHN*CHN) {
            const int pm = idx >> 10, cf = idx & 1023, c = cf >> 5, f = cf & 31;
            raT[(pm << 10) + (f << 5) + c] = bfbits(ra[idx]);   // [pair][m][f][c]
            rmb[idx] = bfbits(rm[idx]);                          // [pair][m][c][f]
        }
    } else {
        const int idx = (blk - 1920)*256 + threadIdx.x;
        if (idx < HEADS*SS*BSTRIDE) {
            const int m = idx / (SS*BSTRIDE);
            const int rem = idx % (SS*BSTRIDE);
            const int s1 = rem / BSTRIDE, s2 = rem % BSTRIDE;
            float val = 0.f;
            if (s2 < SS) {
                const int i1 = s1/49, p1 = s1 - i1*49, h1 = p1/7, w1 = p1 - h1*7;
                const int j2 = s2/49, p2 = s2 - j2*49, h2 = p2/7, w2 = p2 - h2*7;
                const int rc = i1*169 + h1*13 + w1, cc = j2*169 + h2*13 + w2;
                val = bt[(rc - cc + 929)*8 + m];
            }
            biasM[idx] = val;
        }
    }
}

// ---------------- kernel 1: QKV projection via MFMA ----------------
__global__ __launch_bounds__(256) void k_qkv2(
    const float* __restrict__ x, const u16* __restrict__ wT,
    const float* __restrict__ bq, const float* __restrict__ bk, const float* __restrict__ bv,
    const int* __restrict__ atype,
    u16* __restrict__ q, u16* __restrict__ k, u16* __restrict__ v)
{
    __shared__ __align__(16) u16 As[64*ASTRIDE]; // 33792 B
    const int tid = threadIdx.x;
    const int w = tid >> 6, lane = tid & 63;
    const int g4 = lane >> 4, c16 = lane & 15;
    const int bid = blockIdx.x;              // (b*6+l)*64+n
    const int nwin = bid & 63;
    const int l = (bid >> 6) % LL;
    const int b = bid / (LL*NWIN);

    const float4* xp = (const float4*)(x + (size_t)bid * (PP*DIMM));
    for (int idx = tid; idx < 49*64; idx += 256) {
        const int row = idx >> 6, c4 = idx & 63;
        const float4 xv = xp[idx];
        ushort4 h;
        h.x = bfbits(xv.x); h.y = bfbits(xv.y); h.z = bfbits(xv.z); h.w = bfbits(xv.w);
        *(ushort4*)&As[row*ASTRIDE + c4*4] = h;
    }
    const ushort4 z4 = {0, 0, 0, 0};
    for (int idx = tid; idx < 15*66; idx += 256) {
        const int row = 49 + idx/66, c4 = idx%66;
        *(ushort4*)&As[row*ASTRIDE + c4*4] = z4;
    }
    __syncthreads();

    const int t = (l == 0) ? 0 : atype[0];
    const f32x4 zero4 = {0.f, 0.f, 0.f, 0.f};

    for (int tz = 0; tz < 3; ++tz) {
        const u16* WT = wT + (size_t)(tz*2 + t)*65536;
        const float* bias = (tz == 0 ? bq : tz == 1 ? bk : bv) + t*DIMM;
        u16* dst = (tz == 0 ? q : tz == 1 ? k : v);
        const float scale = (tz == 0) ? 0.17677669529663687f : 1.0f;

        f32x4 acc[4][4];
        #pragma unroll
        for (int mm = 0; mm < 4; ++mm)
            #pragma unroll
            for (int nn = 0; nn < 4; ++nn) acc[mm][nn] = zero4;

        for (int ks = 0; ks < 8; ++ks) {
            bf16x8 a[4], bb[4];
            #pragma unroll
            for (int mm = 0; mm < 4; ++mm)
                a[mm] = *(const bf16x8*)&As[(mm*16 + c16)*ASTRIDE + ks*32 + g4*8];
            #pragma unroll
            for (int nn = 0; nn < 4; ++nn)
                bb[nn] = *(const bf16x8*)&WT[(size_t)(w*64 + nn*16 + c16)*256 + ks*32 + g4*8];
            #pragma unroll
            for (int mm = 0; mm < 4; ++mm)
                #pragma unroll
                for (int nn = 0; nn < 4; ++nn)
                    acc[mm][nn] = mfma16(a[mm], bb[nn], acc[mm][nn]);
        }

        #pragma unroll
        for (int nn = 0; nn < 4; ++nn) {
            const int col = w*64 + nn*16 + c16;
            const float bval = bias[col];
            const int head = col >> 5, c = col & 31;
            const size_t base = (((size_t)(b*NWIN + nwin)*HEADS + head)*SS + l*PP)*CHN + c;
            #pragma unroll
            for (int mm = 0; mm < 4; ++mm) {
                #pragma unroll
                for (int r = 0; r < 4; ++r) {
                    const int row = mm*16 + g4*4 + r;
                    if (row < PP)
                        dst[base + (size_t)row*CHN] = bfbits((acc[mm][nn][r] + bval)*scale);
                }
            }
        }
    }
}

// ---------------- kernel 2: MFMA hetero attention per (b,n,m) ----------------
__global__ __launch_bounds__(256, 4) void k_attn(
    const u16* __restrict__ q, const u16* __restrict__ kk_, const u16* __restrict__ v,
    const u16* __restrict__ raT, const u16* __restrict__ rmb,
    const float* __restrict__ biasM, const int* __restrict__ atype,
    u16* __restrict__ o_pre)
{
    __shared__ __align__(16) u16 vT[32*328];     // 20992 B
    __shared__ __align__(16) u16 vT0[32*72];     //  4608 B
    __shared__ __align__(16) u16 qws[4*16*72];   //  9216 B
    __shared__ __align__(16) u16 roll[4*16*40];  //  5120 B  -> total 39936 B, 4 blocks/CU

    const int tid  = threadIdx.x;
    const int w    = tid >> 6;
    const int lane = tid & 63;
    const int g4   = lane >> 4;
    const int c16  = lane & 15;
    const int bid  = blockIdx.x;       // (b*64+n)*8+m
    const int m    = bid & 7;
    const int nwin = (bid >> 3) & 63;
    const int b    = bid >> 9;
    const int at   = atype[0];

    const size_t slab = (size_t)bid * (SS*CHN);
    const u16* qs  = q   + slab;
    const u16* ksg = kk_ + slab;
    const u16* vsg = v   + slab;
    const float* bm = biasM + (size_t)m*(SS*BSTRIDE);

    u16* qws_w  = qws  + w*(16*72);
    u16* roll_w = roll + w*(16*40);

    // ---- zero pads + stage vT/vT0 ----
    for (int idx = tid; idx < 32*26; idx += 256) vT[(idx/26)*328 + 294 + (idx%26)] = 0;
    for (int idx = tid; idx < 32*15; idx += 256) vT0[(idx/15)*72 + 49 + (idx%15)] = 0;
    for (int idx = tid; idx < SS*CHN/2; idx += 256) {
        const int s2 = idx >> 4;
        const int f2 = (idx & 15) << 1;
        const unsigned int val = *(const unsigned int*)(vsg + s2*CHN + f2);
        const u16 v0 = (u16)(val & 0xffff), v1 = (u16)(val >> 16);
        vT[f2*328 + s2] = v0;
        vT[(f2+1)*328 + s2] = v1;
        if (s2 < 49) { vT0[f2*72 + s2] = v0; vT0[(f2+1)*72 + s2] = v1; }
    }
    __syncthreads();

    const f32x4 zero4 = {0.f, 0.f, 0.f, 0.f};

    for (int job = w; job < 20; job += 4) {
        const int tile = (job == 19) ? 3 : job;
        const int tiv  = (job <= 3) ? 0 : at;
        const int pair0 = tiv*2;
        const int pair1 = tiv*2 + at;

        // ---- phase A: qw build ----
        const int rowA = tile*16 + c16;
        const bf16x8 aq = *(const bf16x8*)(qs + rowA*CHN + g4*8);
        f32x4 cqw00, cqw01, cqw10, cqw11;
        {
            const u16* base0 = raT + (pair0*HEADS + m)*1024;
            const u16* base1 = raT + (pair1*HEADS + m)*1024;
            const bf16x8 b00 = *(const bf16x8*)(base0 + (c16     )*32 + g4*8);
            const bf16x8 b01 = *(const bf16x8*)(base0 + (16 + c16)*32 + g4*8);
            const bf16x8 b10 = *(const bf16x8*)(base1 + (c16     )*32 + g4*8);
            const bf16x8 b11 = *(const bf16x8*)(base1 + (16 + c16)*32 + g4*8);
            cqw00 = mfma16(aq, b00, zero4);
            cqw01 = mfma16(aq, b01, zero4);
            cqw10 = mfma16(aq, b10, zero4);
            cqw11 = mfma16(aq, b11, zero4);
        }
        #pragma unroll
        for (int r = 0; r < 4; ++r) {
            const int row = g4*4 + r;
            qws_w[row*72 +      c16] = bfbits(cqw00[r]);
            qws_w[row*72 + 16 + c16] = bfbits(cqw01[r]);
            qws_w[row*72 + 32 + c16] = bfbits(cqw10[r]);
            qws_w[row*72 + 48 + c16] = bfbits(cqw11[r]);
        }
        const bf16x8 A0 = *(const bf16x8*)(qws_w + c16*72 +      g4*8);
        const bf16x8 A1 = *(const bf16x8*)(qws_w + c16*72 + 32 + g4*8);

        // ---- phase B: sim = qw_sel @ k^T ----
        f32x4 acc[19];
        #pragma unroll
        for (int t = 0; t < 3; ++t) {
            const bf16x8 bk = *(const bf16x8*)(ksg + (t*16 + c16)*CHN + g4*8);
            acc[t] = mfma16(A0, bk, zero4);
        }
        {
            const bf16x8 bk = *(const bf16x8*)(ksg + (3*16 + c16)*CHN + g4*8);
            const f32x4 cA = mfma16(A0, bk, zero4);
            const f32x4 cB = mfma16(A1, bk, zero4);
            #pragma unroll
            for (int r = 0; r < 4; ++r) acc[3][r] = (c16 == 0) ? cA[r] : cB[r];
        }
        #pragma unroll
        for (int t = 4; t < 19; ++t) {
            const bf16x8 bk = *(const bf16x8*)(ksg + (t*16 + c16)*CHN + g4*8);
            acc[t] = mfma16(A1, bk, zero4);
        }

        // ---- bias add: coalesced rows from precomputed biasM ----
        const float* bmrow[4];
        #pragma unroll
        for (int r = 0; r < 4; ++r) {
            const int s1r = tile*16 + g4*4 + r;
            const int s1c = (s1r < SS) ? s1r : 293;
            bmrow[r] = bm + (size_t)s1c*BSTRIDE;
        }
        #pragma unroll
        for (int t = 0; t < 19; ++t)
            #pragma unroll
            for (int r = 0; r < 4; ++r)
                acc[t][r] += bmrow[r][t*16 + c16];
        #pragma unroll
        for (int r = 0; r < 4; ++r)
            acc[18][r] = (c16 < 6) ? acc[18][r] : -1e30f;

        // ---- softmax over s2 ----
        float mx[4], sm[4], inv[4];
        #pragma unroll
        for (int r = 0; r < 4; ++r) mx[r] = -1e30f;
        #pragma unroll
        for (int t = 0; t < 19; ++t)
            #pragma unroll
            for (int r = 0; r < 4; ++r) mx[r] = fmaxf(mx[r], acc[t][r]);
        #pragma unroll
        for (int off = 1; off < 16; off <<= 1)
            #pragma unroll
            for (int r = 0; r < 4; ++r) mx[r] = fmaxf(mx[r], __shfl_xor(mx[r], off));
        #pragma unroll
        for (int r = 0; r < 4; ++r) sm[r] = 0.f;
        #pragma unroll
        for (int t = 0; t < 19; ++t)
            #pragma unroll
            for (int r = 0; r < 4; ++r) { const float e = __expf(acc[t][r] - mx[r]); acc[t][r] = e; sm[r] += e; }
        #pragma unroll
        for (int off = 1; off < 16; off <<= 1)
            #pragma unroll
            for (int r = 0; r < 4; ++r) sm[r] += __shfl_xor(sm[r], off);
        #pragma unroll
        for (int r = 0; r < 4; ++r) inv[r] = 1.0f / sm[r];

        // ---- pack attn weights to bf16 pairs in-register (frees acc) ----
        unsigned int pw[19][2];
        #pragma unroll
        for (int t = 0; t < 19; ++t) {
            #pragma unroll
            for (int h = 0; h < 2; ++h) {
                const unsigned int lo = bfbits(acc[t][2*h]   * inv[2*h]);
                const unsigned int hi = bfbits(acc[t][2*h+1] * inv[2*h+1]);
                pw[t][h] = lo | (hi << 16);
            }
        }

        // ---- phase D: PV with rolling tile-pair buffer ----
        f32x4 aggF0 = zero4, aggF1 = zero4, agg00 = zero4, agg01 = zero4;
        bf16x8 asave0, asave1;
        #pragma unroll
        for (int ks = 0; ks < 10; ++ks) {
            #pragma unroll
            for (int r = 0; r < 4; ++r) {
                const int row = g4*4 + r;
                const unsigned int w0 = pw[2*ks][r>>1];
                roll_w[row*40 + c16] = (u16)((r & 1) ? (w0 >> 16) : (w0 & 0xffff));
                const unsigned int w1 = (2*ks + 1 < 19) ? pw[2*ks + 1][r>>1] : 0u;
                roll_w[row*40 + 16 + c16] = (u16)((r & 1) ? (w1 >> 16) : (w1 & 0xffff));
            }
            __builtin_amdgcn_sched_barrier(0);
            const bf16x8 ap  = *(const bf16x8*)(roll_w + c16*40 + g4*8);
            const bf16x8 bv0 = *(const bf16x8*)(vT + (c16     )*328 + ks*32 + g4*8);
            const bf16x8 bv1 = *(const bf16x8*)(vT + (16 + c16)*328 + ks*32 + g4*8);
            aggF0 = mfma16(ap, bv0, aggF0);
            aggF1 = mfma16(ap, bv1, aggF1);
            if (ks == 0) asave0 = ap;
            if (ks == 1) asave1 = ap;
        }
        {
            const bf16x8 b00 = *(const bf16x8*)(vT0 + (c16     )*72 +      g4*8);
            const bf16x8 b01 = *(const bf16x8*)(vT0 + (16 + c16)*72 +      g4*8);
            const bf16x8 b10 = *(const bf16x8*)(vT0 + (c16     )*72 + 32 + g4*8);
            const bf16x8 b11 = *(const bf16x8*)(vT0 + (16 + c16)*72 + 32 + g4*8);
            agg00 = mfma16(asave0, b00, agg00); agg00 = mfma16(asave1, b10, agg00);
            agg01 = mfma16(asave0, b01, agg01); agg01 = mfma16(asave1, b11, agg01);
        }
        const f32x4 agg10 = aggF0 - agg00;
        const f32x4 agg11 = aggF1 - agg01;

        // ---- phase E: msg transform ----
        #pragma unroll
        for (int r = 0; r < 4; ++r) {
            const int row = g4*4 + r;
            qws_w[row*72 +      c16] = bfbits(agg00[r]);
            qws_w[row*72 + 16 + c16] = bfbits(agg01[r]);
            qws_w[row*72 + 32 + c16] = bfbits(agg10[r]);
            qws_w[row*72 + 48 + c16] = bfbits(agg11[r]);
        }
        const bf16x8 aA0 = *(const bf16x8*)(qws_w + c16*72 +      g4*8);
        const bf16x8 aA1 = *(const bf16x8*)(qws_w + c16*72 + 32 + g4*8);
        const u16* mb0 = rmb + (pair0*HEADS + m)*1024;
        const u16* mb1 = rmb + (pair1*HEADS + m)*1024;
        const bf16x8 bm00 = *(const bf16x8*)(mb0 + (c16     )*32 + g4*8);
        const bf16x8 bm01 = *(const bf16x8*)(mb0 + (16 + c16)*32 + g4*8);
        const bf16x8 bm10 = *(const bf16x8*)(mb1 + (c16     )*32 + g4*8);
        const bf16x8 bm11 = *(const bf16x8*)(mb1 + (16 + c16)*32 + g4*8);
        f32x4 out0 = mfma16(aA0, bm00, zero4); out0 = mfma16(aA1, bm10, out0);
        f32x4 out1 = mfma16(aA0, bm01, zero4); out1 = mfma16(aA1, bm11, out1);

        // ---- store bf16 ----
        #pragma unroll
        for (int r = 0; r < 4; ++r) {
            const int s1row = tile*16 + g4*4 + r;
            bool valid = (s1row < SS);
            if (job == 3)  valid = valid && (s1row == 48);
            if (job == 19) valid = valid && (s1row >= 49);
            if (valid) {
                const int i = s1row / 49, p = s1row - i*49;
                const size_t rb = ((size_t)((b*LL + i)*NWIN + nwin)*PP + p)*DIMM + m*CHN;
                o_pre[rb + c16]      = bfbits(out0[r]);
                o_pre[rb + 16 + c16] = bfbits(out1[r]);
            }
        }
    }
}

// ---------------- kernel 3: out = o_pre @ Wo^T via MFMA ----------------
__global__ __launch_bounds__(256) void k_out2(
    const u16* __restrict__ pre, const u16* __restrict__ Wob,
    float* __restrict__ out)
{
    __shared__ __align__(16) u16 As[64*ASTRIDE];
    const int tid = threadIdx.x;
    const int w = tid >> 6, lane = tid & 63;
    const int g4 = lane >> 4, c16 = lane & 15;
    const int bid = blockIdx.x;

    const uint4* pp = (const uint4*)(pre + (size_t)bid * (PP*DIMM));
    for (int idx = tid; idx < 49*32; idx += 256) {
        const int row = idx >> 5, c8 = idx & 31;
        *(uint4*)&As[row*ASTRIDE + c8*8] = pp[idx];
    }
    const ushort4 z4 = {0, 0, 0, 0};
    for (int idx = tid; idx < 15*66; idx += 256) {
        const int row = 49 + idx/66, c4 = idx%66;
        *(ushort4*)&As[row*ASTRIDE + c4*4] = z4;
    }
    __syncthreads();

    const f32x4 zero4 = {0.f, 0.f, 0.f, 0.f};
    f32x4 acc[4][4];
    #pragma unroll
    for (int mm = 0; mm < 4; ++mm)
        #pragma unroll
        for (int nn = 0; nn < 4; ++nn) acc[mm][nn] = zero4;

    for (int ks = 0; ks < 8; ++ks) {
        bf16x8 a[4], bb[4];
        #pragma unroll
        for (int mm = 0; mm < 4; ++mm)
            a[mm] = *(const bf16x8*)&As[(mm*16 + c16)*ASTRIDE + ks*32 + g4*8];
        #pragma unroll
        for (int nn = 0; nn < 4; ++nn)
            bb[nn] = *(const bf16x8*)&Wob[(size_t)(w*64 + nn*16 + c16)*256 + ks*32 + g4*8];
        #pragma unroll
        for (int mm = 0; mm < 4; ++mm)
            #pragma unroll
            for (int nn = 0; nn < 4; ++nn)
                acc[mm][nn] = mfma16(a[mm], bb[nn], acc[mm][nn]);
    }

    float* op = out + (size_t)bid * (PP*DIMM);
    #pragma unroll
    for (int nn = 0; nn < 4; ++nn) {
        const int col = w*64 + nn*16 + c16;
        #pragma unroll
        for (int mm = 0; mm < 4; ++mm) {
            #pragma unroll
            for (int r = 0; r < 4; ++r) {
                const int row = mm*16 + g4*4 + r;
                if (row < PP) op[(size_t)row*DIMM + col] = acc[mm][nn][r];
            }
        }
    }
}

extern "C" void kernel_launch(void* const* d_in, const int* in_sizes, int n_in,
                              void* d_out, int out_size, void* d_ws, size_t ws_size,
                              hipStream_t stream)
{
    (void)in_sizes; (void)n_in; (void)out_size; (void)ws_size;
    const float* x        = (const float*)d_in[0];
    const float* Wq       = (const float*)d_in[1];
    const float* bq       = (const float*)d_in[2];
    const float* Wk       = (const float*)d_in[3];
    const float* bk       = (const float*)d_in[4];
    const float* Wv       = (const float*)d_in[5];
    const float* bv       = (const float*)d_in[6];
    const float* rel_att  = (const float*)d_in[7];
    const float* rel_msg  = (const float*)d_in[8];
    const float* bias_tab = (const float*)d_in[9];
    const float* Wo       = (const float*)d_in[10];
    const int*   atype    = (const int*)d_in[11];
    float* out = (float*)d_out;

    // workspace layout (bytes):
    //  wT    bf16: [0, 786432)
    //  Wob   bf16: [786432, 917504)
    //  raT   bf16: [917504, 983040)
    //  rmb   bf16: [983040, 1048576)
    //  biasM f32 : [1048576, 3908608)      8*294*304*4
    //  qb    bf16: [3908608, +19267584)
    //  kb, vb, o_preb: next               -> total 80,978,944 B
    char* ws = (char*)d_ws;
    u16* wT     = (u16*)ws;
    u16* Wob    = (u16*)(ws + 786432);
    u16* raT    = (u16*)(ws + 917504);
    u16* rmb    = (u16*)(ws + 983040);
    float* biasM= (float*)(ws + 1048576);
    u16* qb     = (u16*)(ws + 3908608);
    u16* kb     = (u16*)(ws + 3908608 + 1ull*19267584);
    u16* vb     = (u16*)(ws + 3908608 + 2ull*19267584);
    u16* o_preb = (u16*)(ws + 3908608 + 3ull*19267584);

    k_prep<<<4713, 256, 0, stream>>>(Wq, Wk, Wv, Wo, rel_att, rel_msg, bias_tab,
                                     wT, Wob, raT, rmb, biasM);
    k_qkv2<<<BB*LL*NWIN, 256, 0, stream>>>(x, wT, bq, bk, bv, atype, qb, kb, vb);
    k_attn<<<BB*NWIN*HEADS, 256, 0, stream>>>(qb, kb, vb, raT, rmb, biasM, atype, o_preb);
    k_out2<<<BB*LL*NWIN, 256, 0, stream>>>(o_preb, Wob, out);
}

// Round 5
// 221.864 us; speedup vs baseline: 1.3605x; 1.3605x over previous
//
#include <hip/hip_runtime.h>
#include <hip/hip_bf16.h>

typedef __hip_bfloat16 bf16;
typedef unsigned short u16;
typedef short bf16x8 __attribute__((ext_vector_type(8)));
typedef float f32x4  __attribute__((ext_vector_type(4)));

// problem constants (fixed instance)
#define BB    2
#define LL    6
#define NWIN  64     // X*Y
#define PP    49     // w1*w2
#define DIMM  256
#define HEADS 8
#define CHN   32
#define SS    294    // LL*PP
#define ASTRIDE 264  // LDS A-tile row stride in u16
#define BSTRIDE 304  // biasM row stride (f32)
#define WBSTRIDE 168 // per-wave strip-half stride in u16 (84 words = 20 mod 32 -> 2-way free)

__device__ __forceinline__ u16 bfbits(float x) { return __bfloat16_as_ushort(__float2bfloat16(x)); }
__device__ __forceinline__ f32x4 mfma16(bf16x8 a, bf16x8 b, f32x4 c) {
    return __builtin_amdgcn_mfma_f32_16x16x32_bf16(a, b, c, 0, 0, 0);
}

// ---------------- merged prep kernel ----------------
__global__ __launch_bounds__(256) void k_prep(
    const float* __restrict__ Wq, const float* __restrict__ Wk, const float* __restrict__ Wv,
    const float* __restrict__ Wo, const float* __restrict__ ra, const float* __restrict__ rm,
    const float* __restrict__ bt,
    u16* __restrict__ wT, u16* __restrict__ Wob, u16* __restrict__ raT, u16* __restrict__ rmb,
    float* __restrict__ biasM)
{
    const int blk = blockIdx.x;
    if (blk < 1792) {
        const int idx = blk*256 + threadIdx.x;
        if (idx >= 7*65536) return;
        const int mat = idx >> 16, rem = idx & 65535;
        if (mat < 6) {
            const int tz = mat >> 1, t = mat & 1;
            const int e = rem >> 8, d = rem & 255;
            const float* W = (tz == 0 ? Wq : tz == 1 ? Wk : Wv);
            wT[mat*65536 + rem] = bfbits(W[t*65536 + d*256 + e]);
        } else {
            Wob[rem] = bfbits(Wo[rem]);
        }
    } else if (blk < 1920) {
        const int idx = (blk - 1792)*256 + threadIdx.x;
        if (idx < 4*HEADS*CHN*CHN) {
            const int pm = idx >> 10, cf = idx & 1023, c = cf >> 5, f = cf & 31;
            raT[(pm << 10) + (f << 5) + c] = bfbits(ra[idx]);   // [pair][m][f][c]
            rmb[idx] = bfbits(rm[idx]);                          // [pair][m][c][f]
        }
    } else {
        const int idx = (blk - 1920)*256 + threadIdx.x;
        if (idx < HEADS*SS*BSTRIDE) {
            const int m = idx / (SS*BSTRIDE);
            const int rem = idx % (SS*BSTRIDE);
            const int s1 = rem / BSTRIDE, s2 = rem % BSTRIDE;
            float val = 0.f;
            if (s2 < SS) {
                const int i1 = s1/49, p1 = s1 - i1*49, h1 = p1/7, w1 = p1 - h1*7;
                const int j2 = s2/49, p2 = s2 - j2*49, h2 = p2/7, w2 = p2 - h2*7;
                const int rc = i1*169 + h1*13 + w1, cc = j2*169 + h2*13 + w2;
                val = bt[(rc - cc + 929)*8 + m];
            }
            biasM[idx] = val;
        }
    }
}

// ---------------- kernel 1: QKV projection via MFMA ----------------
__global__ __launch_bounds__(256) void k_qkv2(
    const float* __restrict__ x, const u16* __restrict__ wT,
    const float* __restrict__ bq, const float* __restrict__ bk, const float* __restrict__ bv,
    const int* __restrict__ atype,
    u16* __restrict__ q, u16* __restrict__ k, u16* __restrict__ v)
{
    __shared__ __align__(16) u16 As[64*ASTRIDE]; // 33792 B
    const int tid = threadIdx.x;
    const int w = tid >> 6, lane = tid & 63;
    const int g4 = lane >> 4, c16 = lane & 15;
    const int bid = blockIdx.x;              // (b*6+l)*64+n
    const int nwin = bid & 63;
    const int l = (bid >> 6) % LL;
    const int b = bid / (LL*NWIN);

    const float4* xp = (const float4*)(x + (size_t)bid * (PP*DIMM));
    for (int idx = tid; idx < 49*64; idx += 256) {
        const int row = idx >> 6, c4 = idx & 63;
        const float4 xv = xp[idx];
        ushort4 h;
        h.x = bfbits(xv.x); h.y = bfbits(xv.y); h.z = bfbits(xv.z); h.w = bfbits(xv.w);
        *(ushort4*)&As[row*ASTRIDE + c4*4] = h;
    }
    const ushort4 z4 = {0, 0, 0, 0};
    for (int idx = tid; idx < 15*66; idx += 256) {
        const int row = 49 + idx/66, c4 = idx%66;
        *(ushort4*)&As[row*ASTRIDE + c4*4] = z4;
    }
    __syncthreads();

    const int t = (l == 0) ? 0 : atype[0];
    const f32x4 zero4 = {0.f, 0.f, 0.f, 0.f};

    for (int tz = 0; tz < 3; ++tz) {
        const u16* WT = wT + (size_t)(tz*2 + t)*65536;
        const float* bias = (tz == 0 ? bq : tz == 1 ? bk : bv) + t*DIMM;
        u16* dst = (tz == 0 ? q : tz == 1 ? k : v);
        const float scale = (tz == 0) ? 0.17677669529663687f : 1.0f;

        f32x4 acc[4][4];
        #pragma unroll
        for (int mm = 0; mm < 4; ++mm)
            #pragma unroll
            for (int nn = 0; nn < 4; ++nn) acc[mm][nn] = zero4;

        for (int ks = 0; ks < 8; ++ks) {
            bf16x8 a[4], bb[4];
            #pragma unroll
            for (int mm = 0; mm < 4; ++mm)
                a[mm] = *(const bf16x8*)&As[(mm*16 + c16)*ASTRIDE + ks*32 + g4*8];
            #pragma unroll
            for (int nn = 0; nn < 4; ++nn)
                bb[nn] = *(const bf16x8*)&WT[(size_t)(w*64 + nn*16 + c16)*256 + ks*32 + g4*8];
            #pragma unroll
            for (int mm = 0; mm < 4; ++mm)
                #pragma unroll
                for (int nn = 0; nn < 4; ++nn)
                    acc[mm][nn] = mfma16(a[mm], bb[nn], acc[mm][nn]);
        }

        #pragma unroll
        for (int nn = 0; nn < 4; ++nn) {
            const int col = w*64 + nn*16 + c16;
            const float bval = bias[col];
            const int head = col >> 5, c = col & 31;
            const size_t base = (((size_t)(b*NWIN + nwin)*HEADS + head)*SS + l*PP)*CHN + c;
            #pragma unroll
            for (int mm = 0; mm < 4; ++mm) {
                #pragma unroll
                for (int r = 0; r < 4; ++r) {
                    const int row = mm*16 + g4*4 + r;
                    if (row < PP)
                        dst[base + (size_t)row*CHN] = bfbits((acc[mm][nn][r] + bval)*scale);
                }
            }
        }
    }
}

// ---------------- kernel 2: MFMA hetero attention per (b,n,m) ----------------
// LDS: vT 20992 B + vT0 4608 B + wbuf 4*16*168*2 = 21504 B  -> 47104 B, 3 blocks/CU
__global__ __launch_bounds__(256) void k_attn(
    const u16* __restrict__ q, const u16* __restrict__ kk_, const u16* __restrict__ v,
    const u16* __restrict__ raT, const u16* __restrict__ rmb,
    const float* __restrict__ biasM, const int* __restrict__ atype,
    u16* __restrict__ o_pre)
{
    __shared__ __align__(16) u16 vT[32*328];
    __shared__ __align__(16) u16 vT0[32*72];
    __shared__ __align__(16) u16 wbuf[4*16*WBSTRIDE]; // per-wave union: qw/agg (stride 72) & strip-half (stride 168)

    const int tid  = threadIdx.x;
    const int w    = tid >> 6;
    const int lane = tid & 63;
    const int g4   = lane >> 4;
    const int c16  = lane & 15;
    const int bid  = blockIdx.x;       // (b*64+n)*8+m
    const int m    = bid & 7;
    const int nwin = (bid >> 3) & 63;
    const int b    = bid >> 9;
    const int at   = atype[0];

    const size_t slab = (size_t)bid * (SS*CHN);
    const u16* qs  = q   + slab;
    const u16* ksg = kk_ + slab;
    const u16* vsg = v   + slab;
    const float* bm = biasM + (size_t)m*(SS*BSTRIDE);

    u16* wb = wbuf + w*(16*WBSTRIDE);

    // ---- zero pads + stage vT/vT0 ----
    for (int idx = tid; idx < 32*26; idx += 256) vT[(idx/26)*328 + 294 + (idx%26)] = 0;
    for (int idx = tid; idx < 32*15; idx += 256) vT0[(idx/15)*72 + 49 + (idx%15)] = 0;
    for (int idx = tid; idx < SS*CHN/2; idx += 256) {
        const int s2 = idx >> 4;
        const int f2 = (idx & 15) << 1;
        const unsigned int val = *(const unsigned int*)(vsg + s2*CHN + f2);
        const u16 v0 = (u16)(val & 0xffff), v1 = (u16)(val >> 16);
        vT[f2*328 + s2] = v0;
        vT[(f2+1)*328 + s2] = v1;
        if (s2 < 49) { vT0[f2*72 + s2] = v0; vT0[(f2+1)*72 + s2] = v1; }
    }
    __syncthreads();

    const f32x4 zero4 = {0.f, 0.f, 0.f, 0.f};

    for (int job = w; job < 20; job += 4) {
        const int tile = (job == 19) ? 3 : job;
        const int tiv  = (job <= 3) ? 0 : at;
        const int pair0 = tiv*2;
        const int pair1 = tiv*2 + at;

        // ---- phase A: qw build (wb as [16][72]) ----
        const int rowA = tile*16 + c16;
        const bf16x8 aq = *(const bf16x8*)(qs + rowA*CHN + g4*8);
        f32x4 cqw00, cqw01, cqw10, cqw11;
        {
            const u16* base0 = raT + (pair0*HEADS + m)*1024;
            const u16* base1 = raT + (pair1*HEADS + m)*1024;
            const bf16x8 b00 = *(const bf16x8*)(base0 + (c16     )*32 + g4*8);
            const bf16x8 b01 = *(const bf16x8*)(base0 + (16 + c16)*32 + g4*8);
            const bf16x8 b10 = *(const bf16x8*)(base1 + (c16     )*32 + g4*8);
            const bf16x8 b11 = *(const bf16x8*)(base1 + (16 + c16)*32 + g4*8);
            cqw00 = mfma16(aq, b00, zero4);
            cqw01 = mfma16(aq, b01, zero4);
            cqw10 = mfma16(aq, b10, zero4);
            cqw11 = mfma16(aq, b11, zero4);
        }
        #pragma unroll
        for (int r = 0; r < 4; ++r) {
            const int row = g4*4 + r;
            wb[row*72 +      c16] = bfbits(cqw00[r]);
            wb[row*72 + 16 + c16] = bfbits(cqw01[r]);
            wb[row*72 + 32 + c16] = bfbits(cqw10[r]);
            wb[row*72 + 48 + c16] = bfbits(cqw11[r]);
        }
        const bf16x8 A0 = *(const bf16x8*)(wb + c16*72 +      g4*8);
        const bf16x8 A1 = *(const bf16x8*)(wb + c16*72 + 32 + g4*8);

        // ---- phase B: sim = qw_sel @ k^T ----
        f32x4 acc[19];
        #pragma unroll
        for (int t = 0; t < 3; ++t) {
            const bf16x8 bk = *(const bf16x8*)(ksg + (t*16 + c16)*CHN + g4*8);
            acc[t] = mfma16(A0, bk, zero4);
        }
        {
            const bf16x8 bk = *(const bf16x8*)(ksg + (3*16 + c16)*CHN + g4*8);
            const f32x4 cA = mfma16(A0, bk, zero4);
            const f32x4 cB = mfma16(A1, bk, zero4);
            #pragma unroll
            for (int r = 0; r < 4; ++r) acc[3][r] = (c16 == 0) ? cA[r] : cB[r];
        }
        #pragma unroll
        for (int t = 4; t < 19; ++t) {
            const bf16x8 bk = *(const bf16x8*)(ksg + (t*16 + c16)*CHN + g4*8);
            acc[t] = mfma16(A1, bk, zero4);
        }

        // ---- bias add: coalesced rows from precomputed biasM ----
        const float* bmrow[4];
        #pragma unroll
        for (int r = 0; r < 4; ++r) {
            const int s1r = tile*16 + g4*4 + r;
            const int s1c = (s1r < SS) ? s1r : 293;
            bmrow[r] = bm + (size_t)s1c*BSTRIDE;
        }
        #pragma unroll
        for (int t = 0; t < 19; ++t)
            #pragma unroll
            for (int r = 0; r < 4; ++r)
                acc[t][r] += bmrow[r][t*16 + c16];
        #pragma unroll
        for (int r = 0; r < 4; ++r)
            acc[18][r] = (c16 < 6) ? acc[18][r] : -1e30f;

        // ---- softmax over s2 ----
        float mx[4], sm[4];
        #pragma unroll
        for (int r = 0; r < 4; ++r) mx[r] = -1e30f;
        #pragma unroll
        for (int t = 0; t < 19; ++t)
            #pragma unroll
            for (int r = 0; r < 4; ++r) mx[r] = fmaxf(mx[r], acc[t][r]);
        #pragma unroll
        for (int off = 1; off < 16; off <<= 1)
            #pragma unroll
            for (int r = 0; r < 4; ++r) mx[r] = fmaxf(mx[r], __shfl_xor(mx[r], off));
        #pragma unroll
        for (int r = 0; r < 4; ++r) sm[r] = 0.f;
        #pragma unroll
        for (int t = 0; t < 19; ++t)
            #pragma unroll
            for (int r = 0; r < 4; ++r) { const float e = __expf(acc[t][r] - mx[r]); acc[t][r] = e; sm[r] += e; }
        #pragma unroll
        for (int off = 1; off < 16; off <<= 1)
            #pragma unroll
            for (int r = 0; r < 4; ++r) sm[r] += __shfl_xor(sm[r], off);
        #pragma unroll
        for (int r = 0; r < 4; ++r) {
            const float inv = 1.0f / sm[r];
            #pragma unroll
            for (int t = 0; t < 19; ++t) acc[t][r] *= inv;
        }

        // ---- phase D pass 1: tiles 0..9 (ks 0..4), wb as [16][168] ----
        f32x4 aggF0a = zero4, aggF0b = zero4, aggF1a = zero4, aggF1b = zero4;
        f32x4 agg00 = zero4, agg01 = zero4;
        bf16x8 asave0, asave1;
        #pragma unroll
        for (int t = 0; t < 10; ++t)
            #pragma unroll
            for (int r = 0; r < 4; ++r)
                wb[(g4*4 + r)*WBSTRIDE + t*16 + c16] = bfbits(acc[t][r]);
        #pragma unroll
        for (int ks = 0; ks < 5; ++ks) {
            const bf16x8 ap  = *(const bf16x8*)(wb + c16*WBSTRIDE + ks*32 + g4*8);
            const bf16x8 bv0 = *(const bf16x8*)(vT + (c16     )*328 + ks*32 + g4*8);
            const bf16x8 bv1 = *(const bf16x8*)(vT + (16 + c16)*328 + ks*32 + g4*8);
            if (ks & 1) { aggF0b = mfma16(ap, bv0, aggF0b); aggF1b = mfma16(ap, bv1, aggF1b); }
            else        { aggF0a = mfma16(ap, bv0, aggF0a); aggF1a = mfma16(ap, bv1, aggF1a); }
            if (ks == 0) asave0 = ap;
            if (ks == 1) asave1 = ap;
        }

        // ---- phase D pass 2: tiles 10..18 + zero pad (ks 5..9) ----
        #pragma unroll
        for (int t2 = 0; t2 < 9; ++t2)
            #pragma unroll
            for (int r = 0; r < 4; ++r)
                wb[(g4*4 + r)*WBSTRIDE + t2*16 + c16] = bfbits(acc[10 + t2][r]);
        #pragma unroll
        for (int r = 0; r < 4; ++r)
            wb[(g4*4 + r)*WBSTRIDE + 9*16 + c16] = 0;
        #pragma unroll
        for (int ks2 = 0; ks2 < 5; ++ks2) {
            const int ks = 5 + ks2;
            const bf16x8 ap  = *(const bf16x8*)(wb + c16*WBSTRIDE + ks2*32 + g4*8);
            const bf16x8 bv0 = *(const bf16x8*)(vT + (c16     )*328 + ks*32 + g4*8);
            const bf16x8 bv1 = *(const bf16x8*)(vT + (16 + c16)*328 + ks*32 + g4*8);
            if (ks2 & 1) { aggF0b = mfma16(ap, bv0, aggF0b); aggF1b = mfma16(ap, bv1, aggF1b); }
            else         { aggF0a = mfma16(ap, bv0, aggF0a); aggF1a = mfma16(ap, bv1, aggF1a); }
        }

        // ---- j=0 part via zero-padded v0 ----
        {
            const bf16x8 b00 = *(const bf16x8*)(vT0 + (c16     )*72 +      g4*8);
            const bf16x8 b01 = *(const bf16x8*)(vT0 + (16 + c16)*72 +      g4*8);
            const bf16x8 b10 = *(const bf16x8*)(vT0 + (c16     )*72 + 32 + g4*8);
            const bf16x8 b11 = *(const bf16x8*)(vT0 + (16 + c16)*72 + 32 + g4*8);
            agg00 = mfma16(asave0, b00, agg00); agg00 = mfma16(asave1, b10, agg00);
            agg01 = mfma16(asave0, b01, agg01); agg01 = mfma16(asave1, b11, agg01);
        }
        const f32x4 aggF0 = aggF0a + aggF0b;
        const f32x4 aggF1 = aggF1a + aggF1b;
        const f32x4 agg10 = aggF0 - agg00;
        const f32x4 agg11 = aggF1 - agg01;

        // ---- phase E: msg transform (wb as [16][72] again) ----
        #pragma unroll
        for (int r = 0; r < 4; ++r) {
            const int row = g4*4 + r;
            wb[row*72 +      c16] = bfbits(agg00[r]);
            wb[row*72 + 16 + c16] = bfbits(agg01[r]);
            wb[row*72 + 32 + c16] = bfbits(agg10[r]);
            wb[row*72 + 48 + c16] = bfbits(agg11[r]);
        }
        const bf16x8 aA0 = *(const bf16x8*)(wb + c16*72 +      g4*8);
        const bf16x8 aA1 = *(const bf16x8*)(wb + c16*72 + 32 + g4*8);
        const u16* mb0 = rmb + (pair0*HEADS + m)*1024;
        const u16* mb1 = rmb + (pair1*HEADS + m)*1024;
        const bf16x8 bm00 = *(const bf16x8*)(mb0 + (c16     )*32 + g4*8);
        const bf16x8 bm01 = *(const bf16x8*)(mb0 + (16 + c16)*32 + g4*8);
        const bf16x8 bm10 = *(const bf16x8*)(mb1 + (c16     )*32 + g4*8);
        const bf16x8 bm11 = *(const bf16x8*)(mb1 + (16 + c16)*32 + g4*8);
        f32x4 out0 = mfma16(aA0, bm00, zero4); out0 = mfma16(aA1, bm10, out0);
        f32x4 out1 = mfma16(aA0, bm01, zero4); out1 = mfma16(aA1, bm11, out1);

        // ---- store bf16 ----
        #pragma unroll
        for (int r = 0; r < 4; ++r) {
            const int s1row = tile*16 + g4*4 + r;
            bool valid = (s1row < SS);
            if (job == 3)  valid = valid && (s1row == 48);
            if (job == 19) valid = valid && (s1row >= 49);
            if (valid) {
                const int i = s1row / 49, p = s1row - i*49;
                const size_t rb = ((size_t)((b*LL + i)*NWIN + nwin)*PP + p)*DIMM + m*CHN;
                o_pre[rb + c16]      = bfbits(out0[r]);
                o_pre[rb + 16 + c16] = bfbits(out1[r]);
            }
        }
    }
}

// ---------------- kernel 3: out = o_pre @ Wo^T via MFMA ----------------
__global__ __launch_bounds__(256) void k_out2(
    const u16* __restrict__ pre, const u16* __restrict__ Wob,
    float* __restrict__ out)
{
    __shared__ __align__(16) u16 As[64*ASTRIDE];
    const int tid = threadIdx.x;
    const int w = tid >> 6, lane = tid & 63;
    const int g4 = lane >> 4, c16 = lane & 15;
    const int bid = blockIdx.x;

    const uint4* pp = (const uint4*)(pre + (size_t)bid * (PP*DIMM));
    for (int idx = tid; idx < 49*32; idx += 256) {
        const int row = idx >> 5, c8 = idx & 31;
        *(uint4*)&As[row*ASTRIDE + c8*8] = pp[idx];
    }
    const ushort4 z4 = {0, 0, 0, 0};
    for (int idx = tid; idx < 15*66; idx += 256) {
        const int row = 49 + idx/66, c4 = idx%66;
        *(ushort4*)&As[row*ASTRIDE + c4*4] = z4;
    }
    __syncthreads();

    const f32x4 zero4 = {0.f, 0.f, 0.f, 0.f};
    f32x4 acc[4][4];
    #pragma unroll
    for (int mm = 0; mm < 4; ++mm)
        #pragma unroll
        for (int nn = 0; nn < 4; ++nn) acc[mm][nn] = zero4;

    for (int ks = 0; ks < 8; ++ks) {
        bf16x8 a[4], bb[4];
        #pragma unroll
        for (int mm = 0; mm < 4; ++mm)
            a[mm] = *(const bf16x8*)&As[(mm*16 + c16)*ASTRIDE + ks*32 + g4*8];
        #pragma unroll
        for (int nn = 0; nn < 4; ++nn)
            bb[nn] = *(const bf16x8*)&Wob[(size_t)(w*64 + nn*16 + c16)*256 + ks*32 + g4*8];
        #pragma unroll
        for (int mm = 0; mm < 4; ++mm)
            #pragma unroll
            for (int nn = 0; nn < 4; ++nn)
                acc[mm][nn] = mfma16(a[mm], bb[nn], acc[mm][nn]);
    }

    float* op = out + (size_t)bid * (PP*DIMM);
    #pragma unroll
    for (int nn = 0; nn < 4; ++nn) {
        const int col = w*64 + nn*16 + c16;
        #pragma unroll
        for (int mm = 0; mm < 4; ++mm) {
            #pragma unroll
            for (int r = 0; r < 4; ++r) {
                const int row = mm*16 + g4*4 + r;
                if (row < PP) op[(size_t)row*DIMM + col] = acc[mm][nn][r];
            }
        }
    }
}

extern "C" void kernel_launch(void* const* d_in, const int* in_sizes, int n_in,
                              void* d_out, int out_size, void* d_ws, size_t ws_size,
                              hipStream_t stream)
{
    (void)in_sizes; (void)n_in; (void)out_size; (void)ws_size;
    const float* x        = (const float*)d_in[0];
    const float* Wq       = (const float*)d_in[1];
    const float* bq       = (const float*)d_in[2];
    const float* Wk       = (const float*)d_in[3];
    const float* bk       = (const float*)d_in[4];
    const float* Wv       = (const float*)d_in[5];
    const float* bv       = (const float*)d_in[6];
    const float* rel_att  = (const float*)d_in[7];
    const float* rel_msg  = (const float*)d_in[8];
    const float* bias_tab = (const float*)d_in[9];
    const float* Wo       = (const float*)d_in[10];
    const int*   atype    = (const int*)d_in[11];
    float* out = (float*)d_out;

    // workspace layout (bytes):
    //  wT    bf16: [0, 786432)
    //  Wob   bf16: [786432, 917504)
    //  raT   bf16: [917504, 983040)
    //  rmb   bf16: [983040, 1048576)
    //  biasM f32 : [1048576, 3908608)
    //  qb, kb, vb, o_preb bf16: 4 x 19267584  -> total 80,978,944 B
    char* ws = (char*)d_ws;
    u16* wT     = (u16*)ws;
    u16* Wob    = (u16*)(ws + 786432);
    u16* raT    = (u16*)(ws + 917504);
    u16* rmb    = (u16*)(ws + 983040);
    float* biasM= (float*)(ws + 1048576);
    u16* qb     = (u16*)(ws + 3908608);
    u16* kb     = (u16*)(ws + 3908608 + 1ull*19267584);
    u16* vb     = (u16*)(ws + 3908608 + 2ull*19267584);
    u16* o_preb = (u16*)(ws + 3908608 + 3ull*19267584);

    k_prep<<<4713, 256, 0, stream>>>(Wq, Wk, Wv, Wo, rel_att, rel_msg, bias_tab,
                                     wT, Wob, raT, rmb, biasM);
    k_qkv2<<<BB*LL*NWIN, 256, 0, stream>>>(x, wT, bq, bk, bv, atype, qb, kb, vb);
    k_attn<<<BB*NWIN*HEADS, 256, 0, stream>>>(qb, kb, vb, raT, rmb, biasM, atype, o_preb);
    k_out2<<<BB*LL*NWIN, 256, 0, stream>>>(o_preb, Wob, out);
}